// Round 1
// baseline (1364.486 us; speedup 1.0000x reference)
//
#include <hip/hip_runtime.h>
#include <math.h>

#define T_LEN 1024
#define BATCH 1024
#define H 64
#define NG 256   // 4*H gate rows
#define NB 4     // batch elements per block

// ---- fast device math (v_exp_f32 / v_rcp_f32, ~1 ulp) ----
__device__ __forceinline__ float fast_rcp(float x) { return __builtin_amdgcn_rcpf(x); }
__device__ __forceinline__ float fast_sigmoid(float x) {
  return fast_rcp(1.0f + __expf(-x));
}
__device__ __forceinline__ float fast_tanh(float x) {
  // overflow-safe: exp of a non-positive argument only
  float a = fabsf(x);
  float e = __expf(-2.0f * a);
  float r = (1.0f - e) * fast_rcp(1.0f + e);
  return copysignf(r, x);
}

// ===================== encoder =====================
// One block handles NB=4 batch elements for all 1024 steps.
// Thread j (0..255) owns gate-row j of Whh_e in registers (64 VGPRs).
// h lives in LDS as [k][b] (b contiguous) -> float4 wave-uniform broadcast reads.
__global__ __launch_bounds__(256, 1) void encoder_kernel(
    const float* __restrict__ x,      // [T, BATCH] (IN=1)
    const float* __restrict__ Wih,    // [256, 1]
    const float* __restrict__ Whh,    // [256, 64]
    const float* __restrict__ bih,    // [256]
    const float* __restrict__ bhh,    // [256]
    float* __restrict__ h_enc)        // [BATCH, 64] out
{
  __shared__ float x_lds[T_LEN * NB];     // 16 KB  [t][b]
  __shared__ float h_lds[H * NB];         // 1 KB   [k][b]
  __shared__ float gate_lds[NB * NG];     // 4 KB   [b][row]

  const int tid = threadIdx.x;            // gate row j
  const int b0 = blockIdx.x * NB;

  // --- persistent weights: row j of Whh (64 floats in VGPRs) ---
  float Wrow[H];
#pragma unroll
  for (int k4 = 0; k4 < H; k4 += 4) {
    const float4 w = *reinterpret_cast<const float4*>(&Whh[tid * H + k4]);
    Wrow[k4 + 0] = w.x; Wrow[k4 + 1] = w.y;
    Wrow[k4 + 2] = w.z; Wrow[k4 + 3] = w.w;
  }
  const float wx = Wih[tid];
  const float bj = bih[tid] + bhh[tid];

  // --- stage this block's x column slice into LDS (one-time 16 KB) ---
  for (int i = tid; i < T_LEN * NB; i += 256) {
    const int t = i >> 2, b = i & 3;
    x_lds[i] = x[t * BATCH + b0 + b];
  }
  // init h = 0 (all 256 slots), c = 0 per role-B thread
  h_lds[tid] = 0.0f;
  const int bB = tid >> 6;     // role-B batch (wave index)
  const int kB = tid & 63;     // role-B hidden unit (lane)
  float c = 0.0f;
  float h_last = 0.0f;
  __syncthreads();

  for (int t = 0; t < T_LEN; ++t) {
    // ---- role A: gate pre-activations for row `tid`, 4 batches ----
    const float4 xv = *reinterpret_cast<const float4*>(&x_lds[t * 4]);
    float a0 = fmaf(wx, xv.x, bj);
    float a1 = fmaf(wx, xv.y, bj);
    float a2 = fmaf(wx, xv.z, bj);
    float a3 = fmaf(wx, xv.w, bj);
#pragma unroll
    for (int k = 0; k < H; ++k) {
      const float4 hv = *reinterpret_cast<const float4*>(&h_lds[k * 4]);  // uniform -> broadcast
      a0 = fmaf(Wrow[k], hv.x, a0);
      a1 = fmaf(Wrow[k], hv.y, a1);
      a2 = fmaf(Wrow[k], hv.z, a2);
      a3 = fmaf(Wrow[k], hv.w, a3);
    }
    gate_lds[0 * NG + tid] = a0;
    gate_lds[1 * NG + tid] = a1;
    gate_lds[2 * NG + tid] = a2;
    gate_lds[3 * NG + tid] = a3;
    __syncthreads();  // gates visible; also: all h_lds reads of this step done

    // ---- role B: cell update for (batch bB, unit kB) ----
    const float gi = gate_lds[bB * NG + kB];
    const float gf = gate_lds[bB * NG + H + kB];
    const float gg = gate_lds[bB * NG + 2 * H + kB];
    const float go = gate_lds[bB * NG + 3 * H + kB];
    const float iv = fast_sigmoid(gi);
    const float fv = fast_sigmoid(gf);
    const float gv = fast_tanh(gg);
    const float ov = fast_sigmoid(go);
    c = fmaf(fv, c, iv * gv);
    h_last = ov * fast_tanh(c);
    h_lds[kB * 4 + bB] = h_last;
    __syncthreads();  // new h visible; gate reads done before next overwrite
  }

  // final hidden state -> workspace, coalesced (lane = kB)
  h_enc[(b0 + bB) * H + kB] = h_last;
}

// ===================== decoder =====================
// hidden=1: per-batch scalar recurrence. One thread per batch element.
__global__ void decoder_kernel(
    const float* __restrict__ h_enc,  // [BATCH, 64]
    const float* __restrict__ Wih,    // [4, 64]
    const float* __restrict__ Whh,    // [4, 1]
    const float* __restrict__ bih,    // [4]
    const float* __restrict__ bhh,    // [4]
    float* __restrict__ out)          // [T, BATCH]
{
  const int b = blockIdx.x * blockDim.x + threadIdx.x;
  if (b >= BATCH) return;

  float a0 = bih[0] + bhh[0];
  float a1 = bih[1] + bhh[1];
  float a2 = bih[2] + bhh[2];
  float a3 = bih[3] + bhh[3];
#pragma unroll 8
  for (int k = 0; k < H; ++k) {
    const float hv = h_enc[b * H + k];
    a0 = fmaf(Wih[0 * H + k], hv, a0);
    a1 = fmaf(Wih[1 * H + k], hv, a1);
    a2 = fmaf(Wih[2 * H + k], hv, a2);
    a3 = fmaf(Wih[3 * H + k], hv, a3);
  }
  const float w0 = Whh[0], w1 = Whh[1], w2 = Whh[2], w3 = Whh[3];

  float h = 0.0f, c = 0.0f;
  for (int t = 0; t < T_LEN; ++t) {
    const float iv = fast_sigmoid(fmaf(w0, h, a0));
    const float fv = fast_sigmoid(fmaf(w1, h, a1));
    const float gv = fast_tanh(fmaf(w2, h, a2));
    const float ov = fast_sigmoid(fmaf(w3, h, a3));
    c = fmaf(fv, c, iv * gv);
    h = ov * fast_tanh(c);
    out[t * BATCH + b] = h;   // coalesced across lanes
  }
}

extern "C" void kernel_launch(void* const* d_in, const int* in_sizes, int n_in,
                              void* d_out, int out_size, void* d_ws, size_t ws_size,
                              hipStream_t stream) {
  const float* x     = (const float*)d_in[0];
  const float* Wih_e = (const float*)d_in[1];
  const float* Whh_e = (const float*)d_in[2];
  const float* bih_e = (const float*)d_in[3];
  const float* bhh_e = (const float*)d_in[4];
  const float* Wih_d = (const float*)d_in[5];
  const float* Whh_d = (const float*)d_in[6];
  const float* bih_d = (const float*)d_in[7];
  const float* bhh_d = (const float*)d_in[8];
  float* out = (float*)d_out;

  float* h_enc = (float*)d_ws;  // 1024*64*4 = 256 KB scratch

  encoder_kernel<<<BATCH / NB, 256, 0, stream>>>(x, Wih_e, Whh_e, bih_e, bhh_e, h_enc);
  decoder_kernel<<<16, 64, 0, stream>>>(h_enc, Wih_d, Whh_d, bih_d, bhh_d, out);
}

// Round 2
// 931.998 us; speedup vs baseline: 1.4640x; 1.4640x over previous
//
#include <hip/hip_runtime.h>
#include <math.h>

#define T_LEN 1024
#define BATCH 1024
#define H 64

// ---- fast device math (v_exp_f32 / v_rcp_f32) ----
__device__ __forceinline__ float fast_rcp(float x) { return __builtin_amdgcn_rcpf(x); }
__device__ __forceinline__ float fast_sigmoid(float x) {
  return fast_rcp(1.0f + __expf(-x));
}
__device__ __forceinline__ float fast_tanh(float x) {
  float a = fabsf(x);
  float e = __expf(-2.0f * a);
  float r = (1.0f - e) * fast_rcp(1.0f + e);
  return copysignf(r, x);
}

__device__ __forceinline__ float bcast_lane(float v, int k) {
  return __int_as_float(__builtin_amdgcn_readlane(__float_as_int(v), k));
}

// ===================== encoder =====================
// One WAVE per batch element; 4 waves (4 batches) per block; grid = 256.
// Lane j owns hidden unit j: c[j], h[j], and gate rows {j, 64+j, 128+j, 192+j}
// of Whh in 256 VGPRs. h_k broadcast via v_readlane (VALU) — the t-loop has
// NO LDS traffic except one uniform ds_read_b32 for x[t], and NO barriers.
__global__ __launch_bounds__(256, 1) void encoder_kernel(
    const float* __restrict__ x,      // [T, BATCH] (IN=1)
    const float* __restrict__ Wih,    // [256, 1]
    const float* __restrict__ Whh,    // [256, 64]
    const float* __restrict__ bih,    // [256]
    const float* __restrict__ bhh,    // [256]
    float* __restrict__ h_enc)        // [BATCH, 64] out
{
  __shared__ float x_lds[4][T_LEN];   // 16 KB, one row per wave

  const int tid  = threadIdx.x;
  const int lane = tid & 63;
  const int w    = tid >> 6;
  const int b    = blockIdx.x * 4 + w;

  // --- persistent weights: 4 gate rows for hidden unit `lane` (256 VGPRs) ---
  float W0[H], W1[H], W2[H], W3[H];
#pragma unroll
  for (int k4 = 0; k4 < H; k4 += 4) {
    const float4 q0 = *reinterpret_cast<const float4*>(&Whh[(0 * H + lane) * H + k4]);
    const float4 q1 = *reinterpret_cast<const float4*>(&Whh[(1 * H + lane) * H + k4]);
    const float4 q2 = *reinterpret_cast<const float4*>(&Whh[(2 * H + lane) * H + k4]);
    const float4 q3 = *reinterpret_cast<const float4*>(&Whh[(3 * H + lane) * H + k4]);
    W0[k4] = q0.x; W0[k4 + 1] = q0.y; W0[k4 + 2] = q0.z; W0[k4 + 3] = q0.w;
    W1[k4] = q1.x; W1[k4 + 1] = q1.y; W1[k4 + 2] = q1.z; W1[k4 + 3] = q1.w;
    W2[k4] = q2.x; W2[k4 + 1] = q2.y; W2[k4 + 2] = q2.z; W2[k4 + 3] = q2.w;
    W3[k4] = q3.x; W3[k4 + 1] = q3.y; W3[k4 + 2] = q3.z; W3[k4 + 3] = q3.w;
  }
  const float wx0 = Wih[0 * H + lane], wx1 = Wih[1 * H + lane];
  const float wx2 = Wih[2 * H + lane], wx3 = Wih[3 * H + lane];
  const float bj0 = bih[0 * H + lane] + bhh[0 * H + lane];
  const float bj1 = bih[1 * H + lane] + bhh[1 * H + lane];
  const float bj2 = bih[2 * H + lane] + bhh[2 * H + lane];
  const float bj3 = bih[3 * H + lane] + bhh[3 * H + lane];

  // --- stage this wave's x column (wave-private; no cross-wave sharing) ---
#pragma unroll
  for (int i = 0; i < T_LEN / 64; ++i) {
    const int t = i * 64 + lane;
    x_lds[w][t] = x[t * BATCH + b];
  }
  __syncthreads();  // drains vm/lgkm; waves are otherwise independent

  float h = 0.0f, c = 0.0f;

  for (int t = 0; t < T_LEN; ++t) {
    const float xt = x_lds[w][t];   // wave-uniform -> single broadcast read
    float a0 = fmaf(wx0, xt, bj0);
    float a1 = fmaf(wx1, xt, bj1);
    float a2 = fmaf(wx2, xt, bj2);
    float a3 = fmaf(wx3, xt, bj3);
#pragma unroll
    for (int k = 0; k < H; ++k) {
      const float hk = bcast_lane(h, k);   // v_readlane -> SGPR, no LDS
      a0 = fmaf(W0[k], hk, a0);
      a1 = fmaf(W1[k], hk, a1);
      a2 = fmaf(W2[k], hk, a2);
      a3 = fmaf(W3[k], hk, a3);
    }
    const float iv = fast_sigmoid(a0);
    const float fv = fast_sigmoid(a1);
    const float gv = fast_tanh(a2);
    const float ov = fast_sigmoid(a3);
    c = fmaf(fv, c, iv * gv);
    h = ov * fast_tanh(c);
  }

  h_enc[b * H + lane] = h;  // coalesced
}

// ===================== decoder =====================
// hidden=1: per-batch scalar recurrence. One thread per batch element.
__global__ void decoder_kernel(
    const float* __restrict__ h_enc,  // [BATCH, 64]
    const float* __restrict__ Wih,    // [4, 64]
    const float* __restrict__ Whh,    // [4, 1]
    const float* __restrict__ bih,    // [4]
    const float* __restrict__ bhh,    // [4]
    float* __restrict__ out)          // [T, BATCH]
{
  const int b = blockIdx.x * blockDim.x + threadIdx.x;
  if (b >= BATCH) return;

  float a0 = bih[0] + bhh[0];
  float a1 = bih[1] + bhh[1];
  float a2 = bih[2] + bhh[2];
  float a3 = bih[3] + bhh[3];
#pragma unroll 8
  for (int k = 0; k < H; ++k) {
    const float hv = h_enc[b * H + k];
    a0 = fmaf(Wih[0 * H + k], hv, a0);
    a1 = fmaf(Wih[1 * H + k], hv, a1);
    a2 = fmaf(Wih[2 * H + k], hv, a2);
    a3 = fmaf(Wih[3 * H + k], hv, a3);
  }
  const float w0 = Whh[0], w1 = Whh[1], w2 = Whh[2], w3 = Whh[3];

  float h = 0.0f, c = 0.0f;
  for (int t = 0; t < T_LEN; ++t) {
    const float iv = fast_sigmoid(fmaf(w0, h, a0));
    const float fv = fast_sigmoid(fmaf(w1, h, a1));
    const float gv = fast_tanh(fmaf(w2, h, a2));
    const float ov = fast_sigmoid(fmaf(w3, h, a3));
    c = fmaf(fv, c, iv * gv);
    h = ov * fast_tanh(c);
    out[t * BATCH + b] = h;   // coalesced across lanes
  }
}

extern "C" void kernel_launch(void* const* d_in, const int* in_sizes, int n_in,
                              void* d_out, int out_size, void* d_ws, size_t ws_size,
                              hipStream_t stream) {
  const float* x     = (const float*)d_in[0];
  const float* Wih_e = (const float*)d_in[1];
  const float* Whh_e = (const float*)d_in[2];
  const float* bih_e = (const float*)d_in[3];
  const float* bhh_e = (const float*)d_in[4];
  const float* Wih_d = (const float*)d_in[5];
  const float* Whh_d = (const float*)d_in[6];
  const float* bih_d = (const float*)d_in[7];
  const float* bhh_d = (const float*)d_in[8];
  float* out = (float*)d_out;

  float* h_enc = (float*)d_ws;  // 1024*64*4 = 256 KB scratch

  encoder_kernel<<<BATCH / 4, 256, 0, stream>>>(x, Wih_e, Whh_e, bih_e, bhh_e, h_enc);
  decoder_kernel<<<16, 64, 0, stream>>>(h_enc, Wih_d, Whh_d, bih_d, bhh_d, out);
}

// Round 3
// 886.218 us; speedup vs baseline: 1.5397x; 1.0517x over previous
//
#include <hip/hip_runtime.h>
#include <math.h>

#define T_LEN 1024
#define BATCH 1024
#define H 64

// ---- fast device math (v_exp_f32 / v_rcp_f32) ----
__device__ __forceinline__ float fast_rcp(float x) { return __builtin_amdgcn_rcpf(x); }
__device__ __forceinline__ float fast_sigmoid(float x) {
  return fast_rcp(1.0f + __expf(-x));
}
__device__ __forceinline__ float fast_tanh(float x) {
  float a = fabsf(x);
  float e = __expf(-2.0f * a);
  float r = (1.0f - e) * fast_rcp(1.0f + e);
  return copysignf(r, x);
}

__device__ __forceinline__ float bcast_lane(float v, int k) {
  return __int_as_float(__builtin_amdgcn_readlane(__float_as_int(v), k));
}

// ===================== encoder =====================
// One block (128 threads = 2 waves) per batch element; grid = 1024.
// K-split: wave w covers k in [32w, 32w+32) for ALL 4 gates.
// Lane j owns gate rows {j, 64+j, 128+j, 192+j} (its k-half): 128 VGPRs of
// weights -> fits 2 waves/SIMD with NO AGPR spill (the R2 killer).
// Per step: 128 FMA + 32 readlane + b128 partial exchange + redundant cell.
__global__ __launch_bounds__(128, 2) void encoder_kernel(
    const float* __restrict__ x,      // [T, BATCH] (IN=1)
    const float* __restrict__ Wih,    // [256, 1]
    const float* __restrict__ Whh,    // [256, 64]
    const float* __restrict__ bih,    // [256]
    const float* __restrict__ bhh,    // [256]
    float* __restrict__ h_enc)        // [BATCH, 64] out
{
  __shared__ float  x_lds[T_LEN];        // 4 KB
  __shared__ float4 pbuf[2][2][64];      // 4 KB: [parity][wave][lane]

  const int tid  = threadIdx.x;
  const int lane = tid & 63;
  const int w    = tid >> 6;             // 0 or 1 (k-half)
  const int b    = blockIdx.x;

  // --- persistent weights: 4 gates x 32 k-slice (128 VGPRs) ---
  float W0[32], W1[32], W2[32], W3[32];
#pragma unroll
  for (int k4 = 0; k4 < 32; k4 += 4) {
    const float4 q0 = *reinterpret_cast<const float4*>(&Whh[(0 * H + lane) * H + w * 32 + k4]);
    const float4 q1 = *reinterpret_cast<const float4*>(&Whh[(1 * H + lane) * H + w * 32 + k4]);
    const float4 q2 = *reinterpret_cast<const float4*>(&Whh[(2 * H + lane) * H + w * 32 + k4]);
    const float4 q3 = *reinterpret_cast<const float4*>(&Whh[(3 * H + lane) * H + w * 32 + k4]);
    W0[k4] = q0.x; W0[k4 + 1] = q0.y; W0[k4 + 2] = q0.z; W0[k4 + 3] = q0.w;
    W1[k4] = q1.x; W1[k4 + 1] = q1.y; W1[k4 + 2] = q1.z; W1[k4 + 3] = q1.w;
    W2[k4] = q2.x; W2[k4 + 1] = q2.y; W2[k4 + 2] = q2.z; W2[k4 + 3] = q2.w;
    W3[k4] = q3.x; W3[k4 + 1] = q3.y; W3[k4 + 2] = q3.z; W3[k4 + 3] = q3.w;
  }
  const float wx0 = Wih[0 * H + lane], wx1 = Wih[1 * H + lane];
  const float wx2 = Wih[2 * H + lane], wx3 = Wih[3 * H + lane];
  const float bj0 = bih[0 * H + lane] + bhh[0 * H + lane];
  const float bj1 = bih[1 * H + lane] + bhh[1 * H + lane];
  const float bj2 = bih[2 * H + lane] + bhh[2 * H + lane];
  const float bj3 = bih[3 * H + lane] + bhh[3 * H + lane];

  // --- stage x column for this batch (one-time) ---
  for (int i = tid; i < T_LEN; i += 128) x_lds[i] = x[i * BATCH + b];
  __syncthreads();

  float h = 0.0f, c = 0.0f;

  for (int t = 0; t < T_LEN; ++t) {
    float a0, a1, a2, a3;
    if (w == 0) {
      const float xt = x_lds[t];
      a0 = fmaf(wx0, xt, bj0);
      a1 = fmaf(wx1, xt, bj1);
      a2 = fmaf(wx2, xt, bj2);
      a3 = fmaf(wx3, xt, bj3);
#pragma unroll
      for (int kk = 0; kk < 32; ++kk) {
        const float hk = bcast_lane(h, kk);      // constant lane index
        a0 = fmaf(W0[kk], hk, a0);
        a1 = fmaf(W1[kk], hk, a1);
        a2 = fmaf(W2[kk], hk, a2);
        a3 = fmaf(W3[kk], hk, a3);
      }
    } else {
      a0 = a1 = a2 = a3 = 0.0f;
#pragma unroll
      for (int kk = 0; kk < 32; ++kk) {
        const float hk = bcast_lane(h, 32 + kk); // constant lane index
        a0 = fmaf(W0[kk], hk, a0);
        a1 = fmaf(W1[kk], hk, a1);
        a2 = fmaf(W2[kk], hk, a2);
        a3 = fmaf(W3[kk], hk, a3);
      }
    }

    // exchange partial sums with partner wave (1 barrier/step, parity dbuf)
    pbuf[t & 1][w][lane] = make_float4(a0, a1, a2, a3);
    __syncthreads();
    const float4 p = pbuf[t & 1][1 - w][lane];
    a0 += p.x; a1 += p.y; a2 += p.z; a3 += p.w;

    // cell update (redundant in both waves; wave-wide cost is identical)
    const float iv = fast_sigmoid(a0);
    const float fv = fast_sigmoid(a1);
    const float gv = fast_tanh(a2);
    const float ov = fast_sigmoid(a3);
    c = fmaf(fv, c, iv * gv);
    h = ov * fast_tanh(c);
  }

  if (w == 0) h_enc[b * H + lane] = h;  // coalesced
}

// ===================== decoder =====================
// hidden=1: per-batch scalar recurrence. One thread per batch element.
__global__ void decoder_kernel(
    const float* __restrict__ h_enc,  // [BATCH, 64]
    const float* __restrict__ Wih,    // [4, 64]
    const float* __restrict__ Whh,    // [4, 1]
    const float* __restrict__ bih,    // [4]
    const float* __restrict__ bhh,    // [4]
    float* __restrict__ out)          // [T, BATCH]
{
  const int b = blockIdx.x * blockDim.x + threadIdx.x;
  if (b >= BATCH) return;

  float a0 = bih[0] + bhh[0];
  float a1 = bih[1] + bhh[1];
  float a2 = bih[2] + bhh[2];
  float a3 = bih[3] + bhh[3];
#pragma unroll 8
  for (int k = 0; k < H; ++k) {
    const float hv = h_enc[b * H + k];
    a0 = fmaf(Wih[0 * H + k], hv, a0);
    a1 = fmaf(Wih[1 * H + k], hv, a1);
    a2 = fmaf(Wih[2 * H + k], hv, a2);
    a3 = fmaf(Wih[3 * H + k], hv, a3);
  }
  const float w0 = Whh[0], w1 = Whh[1], w2 = Whh[2], w3 = Whh[3];

  float h = 0.0f, c = 0.0f;
  for (int t = 0; t < T_LEN; ++t) {
    const float iv = fast_sigmoid(fmaf(w0, h, a0));
    const float fv = fast_sigmoid(fmaf(w1, h, a1));
    const float gv = fast_tanh(fmaf(w2, h, a2));
    const float ov = fast_sigmoid(fmaf(w3, h, a3));
    c = fmaf(fv, c, iv * gv);
    h = ov * fast_tanh(c);
    out[t * BATCH + b] = h;   // coalesced across lanes
  }
}

extern "C" void kernel_launch(void* const* d_in, const int* in_sizes, int n_in,
                              void* d_out, int out_size, void* d_ws, size_t ws_size,
                              hipStream_t stream) {
  const float* x     = (const float*)d_in[0];
  const float* Wih_e = (const float*)d_in[1];
  const float* Whh_e = (const float*)d_in[2];
  const float* bih_e = (const float*)d_in[3];
  const float* bhh_e = (const float*)d_in[4];
  const float* Wih_d = (const float*)d_in[5];
  const float* Whh_d = (const float*)d_in[6];
  const float* bih_d = (const float*)d_in[7];
  const float* bhh_d = (const float*)d_in[8];
  float* out = (float*)d_out;

  float* h_enc = (float*)d_ws;  // 1024*64*4 = 256 KB scratch

  encoder_kernel<<<BATCH, 128, 0, stream>>>(x, Wih_e, Whh_e, bih_e, bhh_e, h_enc);
  decoder_kernel<<<16, 64, 0, stream>>>(h_enc, Wih_d, Whh_d, bih_d, bhh_d, out);
}